// Round 24
// baseline (206.965 us; speedup 1.0000x reference)
//
#include <hip/hip_runtime.h>
#include <hip/hip_bf16.h>

typedef __attribute__((ext_vector_type(8))) short bf16x8;
typedef __attribute__((ext_vector_type(4))) short s16x4;
typedef __attribute__((ext_vector_type(4))) float f32x4;
typedef __attribute__((ext_vector_type(4))) float float4v;

static __device__ __forceinline__ unsigned short f2b(float f) {
  unsigned int u = __builtin_bit_cast(unsigned int, f);
  u += 0x7fffu + ((u >> 16) & 1u);
  return (unsigned short)(u >> 16);
}
static __device__ __forceinline__ float b2f(unsigned short s) {
  unsigned int u = ((unsigned int)s) << 16;
  return __builtin_bit_cast(float, u);
}
// fast silu/softplus on TRANS pipe; bf16-accurate
static __device__ __forceinline__ float fsilu(float x) {
  float e = __builtin_amdgcn_exp2f(-1.44269504f * x);
  return x * __builtin_amdgcn_rcpf(1.f + e);
}
static __device__ __forceinline__ float fsoftplus(float a) {
  if (a > 20.f) return a;
  float t = __builtin_amdgcn_exp2f(1.44269504f * a);
  return 0.69314718f * __builtin_amdgcn_logf(1.f + t);
}
// async global->LDS, 16B/lane; dest wave-uniform base + lane*16,
// source per-lane (enables source-side swizzling, rule #21)
static __device__ __forceinline__ void gl16(const void* g, void* l) {
  __builtin_amdgcn_global_load_lds(
      (const __attribute__((address_space(1))) unsigned int*)g,
      (__attribute__((address_space(3))) unsigned int*)l, 16, 0, 0);
}
template <int N>
static __device__ __forceinline__ void waitv() {
  if constexpr (N == 0) asm volatile("s_waitcnt vmcnt(0)" ::: "memory");
  else if constexpr (N == 1) asm volatile("s_waitcnt vmcnt(1)" ::: "memory");
  else if constexpr (N == 2) asm volatile("s_waitcnt vmcnt(2)" ::: "memory");
  else if constexpr (N == 3) asm volatile("s_waitcnt vmcnt(3)" ::: "memory");
  else if constexpr (N == 4) asm volatile("s_waitcnt vmcnt(4)" ::: "memory");
  else if constexpr (N == 5) asm volatile("s_waitcnt vmcnt(5)" ::: "memory");
  else if constexpr (N == 6) asm volatile("s_waitcnt vmcnt(6)" ::: "memory");
  else if constexpr (N == 7) asm volatile("s_waitcnt vmcnt(7)" ::: "memory");
  else if constexpr (N == 8) asm volatile("s_waitcnt vmcnt(8)" ::: "memory");
}
static __device__ __forceinline__ void lgkm_bar() {
  asm volatile("s_waitcnt lgkmcnt(0)" ::: "memory");
  __builtin_amdgcn_s_barrier();
}

// ---------------------------------------------------------------------------
// pre-GEMM: C = A @ W^T + bias, bf16 MFMA, fp32 accum. 128x64, BK=32,
// 4 waves, depth-4 ring, counted vmcnt, chunk-XOR swizzle, XCD swizzle.
// ---------------------------------------------------------------------------
template <int TM, int TN>
__global__ __launch_bounds__(256) void gemm_pl(
    const unsigned short* __restrict__ A, const unsigned short* __restrict__ W,
    int N, int K, int GY,
    const float* __restrict__ p0, float* __restrict__ of,
    unsigned short* __restrict__ ob) {
  constexpr int FM = TM / 32, FN = TN / 32;
  constexpr int IA = TM / 64, IW = TN / 64;
  constexpr int LPT = IA + IW;
  __shared__ __align__(16) unsigned short As[4][TM * 32];
  __shared__ __align__(16) unsigned short Ws[4][TN * 32];

  const int t = threadIdx.x, lane = t & 63, wave = t >> 6;
  const int lr = lane & 15;
  const int q = gridDim.x >> 3;
  const int s = (blockIdx.x & 7) * q + (blockIdx.x >> 3);
  const int bm = (s / GY) * TM, bn = (s % GY) * TN;
  const int wr = (wave >> 1) * (TM / 2), wc = (wave & 1) * (TN / 2);

  f32x4 acc[FM][FN];
#pragma unroll
  for (int i = 0; i < FM; ++i)
#pragma unroll
    for (int j = 0; j < FN; ++j) acc[i][j] = (f32x4){0.f, 0.f, 0.f, 0.f};

  const unsigned short* agB =
      A + (long)(bm + wave * (TM / 4) + (lane >> 2)) * K +
      ((lane & 3) ^ ((lane >> 3) & 3)) * 8;
  const unsigned short* wgB =
      W + (long)(bn + wave * (TN / 4) + (lane >> 2)) * K +
      ((lane & 3) ^ ((lane >> 3) & 3)) * 8;

  auto STAGE = [&](int k0, int b) {
#pragma unroll
    for (int j = 0; j < IA; ++j)
      gl16(agB + k0 + (long)j * 16 * K, &As[b][(wave * (TM / 4) + j * 16) * 32]);
#pragma unroll
    for (int j = 0; j < IW; ++j)
      gl16(wgB + k0 + (long)j * 16 * K, &Ws[b][(wave * (TN / 4) + j * 16) * 32]);
  };

  auto COMPUTE = [&](int b) {
    bf16x8 af[FM], bg[FN];
    const int sw = ((lane >> 4) ^ ((lane >> 1) & 3)) * 8;
#pragma unroll
    for (int m = 0; m < FM; ++m)
      af[m] = *(const bf16x8*)&As[b][(wr + m * 16 + lr) * 32 + sw];
#pragma unroll
    for (int n = 0; n < FN; ++n)
      bg[n] = *(const bf16x8*)&Ws[b][(wc + n * 16 + lr) * 32 + sw];
    __builtin_amdgcn_s_setprio(1);
#pragma unroll
    for (int m = 0; m < FM; ++m)
#pragma unroll
      for (int n = 0; n < FN; ++n)
        acc[m][n] = __builtin_amdgcn_mfma_f32_16x16x32_bf16(af[m], bg[n],
                                                            acc[m][n], 0, 0, 0);
    __builtin_amdgcn_s_setprio(0);
  };

  const int NT = K >> 5;
  STAGE(0, 0);
  STAGE(32, 1);
  for (int tt = 0; tt < NT; ++tt) {
    if (tt + 2 < NT) {
      STAGE((tt + 2) << 5, (tt + 2) & 3);
      waitv<2 * LPT>();
    } else if (tt + 1 < NT) {
      waitv<LPT>();
    } else {
      waitv<0>();
    }
    __builtin_amdgcn_s_barrier();
    COMPUTE(tt & 3);
    __builtin_amdgcn_sched_barrier(0);
  }

  const int m0 = bm + wr + (lane >> 4) * 4;
  const int n0 = bn + wc + lr;
#pragma unroll
  for (int mi = 0; mi < FM; ++mi)
#pragma unroll
    for (int ni = 0; ni < FN; ++ni) {
      const int n = n0 + ni * 16;
#pragma unroll
      for (int r = 0; r < 4; ++r) {
        const int m = m0 + mi * 16 + r;
        float v = acc[mi][ni][r] + p0[n];
        of[(long)m * N + n] = v;
        ob[(long)m * N + n] = f2b(v);
      }
    }
}

// ---------------------------------------------------------------------------
// mamba5: 5 Mamba blocks fused + FUSED LayerNorm/classifier epilogue.
// Grid 256 x 512thr, 32 rows/block, h resident. r13 main structure:
// DEPTH-7 pipeline, tiles [128N x 32K] = 8KB, Ring = 8 x 8KB, 1 gl16 per
// wave per tile. Tile swizzle chunk ^= (row>>1)&3 both-sides. No global
// loads in loops (conv tap3 folded into inwb; cb/dtb/D in Par LDS).
// L=1: conv=tap3*xi+cb; scan -> y=xi*(dt*BC+D)*silu(z).
// Cross-phase hiding (all slot-audited, race-free, issued OUTSIDE loops):
//  - next blk's P1 tiles 0..6 staged in P5 tail (slots 0..6; slot 7 still
//    read at tt=31, untouched). Par staged at blk-loop top by all 8 waves
//    (seg mirror) -> P1 waits vmcnt(7) for tt<7, vmcnt(6) after (Par
//    retires at tt=7); conv-bias applied at kq==7 epilogue (Par resident).
//  - xwp (rows 0..47 -> slots 0..5) issued after P1 loop, before lgkm_bar.
//  - dtwp split: half1 -> Ring[24576..) under P2 (waitv<2>); half2 ->
//    Ring[0..8192) after P2. P4 reads switch base on tt<4.
// SzL shares XiL's chunk-XOR swizzle both-sides.
// SMEM (shorts): XiL[0,16384) SzL[16384,32768) Ring[32768,65536)
//   HLr[65536,73728) Dxl@73728(32x68 f32) BCl@78080 Par@78144(1536 f32)
// ---------------------------------------------------------------------------
__global__ __launch_bounds__(512) void mamba5(
    const unsigned short* __restrict__ hb0, const float* __restrict__ h0,
    const unsigned short* __restrict__ inwb,
    const unsigned short* __restrict__ xwpb,
    const unsigned short* __restrict__ dtwpb,
    const unsigned short* __restrict__ owb,
    const float* __restrict__ conv_b, const float* __restrict__ dt_b,
    const float* __restrict__ Dp,
    const float* __restrict__ ln_g, const float* __restrict__ ln_b,
    const float* __restrict__ Wc, const float* __restrict__ bc,
    float* __restrict__ out) {
  __shared__ __align__(16) unsigned short SMEM[81216];
  unsigned short* XiL = SMEM;
  unsigned short* SzL = SMEM + 16384;
  unsigned short* Ring = SMEM + 32768;
  unsigned short* HLr = SMEM + 65536;
  float* Dxl = (float*)(SMEM + 73728);
  float* BCl = (float*)(SMEM + 78080);
  float* Par = (float*)(SMEM + 78144);

  const int t = threadIdx.x, lane = t & 63, w = t >> 6;
  const int lr = lane & 15, lg = lane >> 4;
  const int bm = blockIdx.x * 32;
  const int m04 = lg * 4;             // frag row base within 16-row block
  const int rg16 = (w >> 2) * 16;     // wave's row group: 0 / 16
  const int cg32 = (w & 3) * 32;      // wave's col group within 128-col tile
  const int strow = lane >> 2;        // staging row within 16-row group
  const int stc = (lane & 3) ^ ((strow >> 1) & 3);  // pre-swizzled src chunk
  const int seg = (w < 6) ? w : (w - 2);  // Par segment (w6/7 mirror w4/5)

  // ---- init: h bf16 -> HLr (chunk-swizzled); fp32 residual -> regs ----
#pragma unroll
  for (int j = 0; j < 2; ++j) {
    const int i = w * 2 + j;
    const int row = 2 * i + (lane >> 5);
    const int c = (lane & 31) ^ (row & 7);
    gl16(hb0 + (long)(bm + row) * 256 + c * 8, HLr + i * 512);
  }
  float hres[2][2][4];
#pragma unroll
  for (int ng = 0; ng < 2; ++ng)
#pragma unroll
    for (int n = 0; n < 2; ++n)
#pragma unroll
      for (int r = 0; r < 4; ++r)
        hres[ng][n][r] = h0[(long)(bm + rg16 + m04 + r) * 256 + ng * 128 +
                            cg32 + n * 16 + lr];
  waitv<0>();
  __builtin_amdgcn_s_barrier();

  // ---- blk0 P1 prologue: tiles 0..6 into slots 0..6 (Par at loop top) ----
#pragma unroll
  for (int j = 0; j < 7; ++j)
    gl16(inwb + (long)(w * 16 + strow) * 256 + j * 32 + stc * 8,
         Ring + j * 4096 + w * 512);

  for (int blk = 0; blk < 5; ++blk) {
    const unsigned short* inw = inwb + (long)blk * 1024 * 256;
    const unsigned short* xwp = xwpb + (long)blk * 64 * 512;
    const unsigned short* dtwp = dtwpb + (long)blk * 512 * 32;
    const unsigned short* ow = owb + (long)blk * 256 * 512;
    const float* cbv = conv_b + blk * 512;
    const float* dtbv = dt_b + blk * 512;
    const float* Dv = Dp + blk * 512;

    // Par for this blk (all 8 waves; w6/7 mirror w4/5 -> uniform vmcnt)
    {
      const float* ps = (seg < 2) ? cbv + (seg & 1) * 256
                      : (seg < 4) ? dtbv + (seg & 1) * 256
                                  : Dv + (seg & 1) * 256;
      gl16(ps + lane * 4, (unsigned short*)Par + seg * 512);
    }

    // ===== P1: xz = h @ in_w'^T. 64 tiles [128N x 32K], depth-7 =====
    auto STAGE1 = [&](int tt, int slot) {
      const int nt = tt >> 3, kq = tt & 7;
      gl16(inw + (long)(nt * 128 + w * 16 + strow) * 256 + kq * 32 + stc * 8,
           Ring + slot * 4096 + w * 512);
    };
    f32x4 acc1[2];
#pragma unroll
    for (int tt = 0; tt < 64; ++tt) {
      if (tt < 7) waitv<7>();        // Par (newest) still in flight
      else if (tt <= 57) waitv<6>(); // Par retired at tt==7
      else if (tt == 58) waitv<5>();
      else if (tt == 59) waitv<4>();
      else if (tt == 60) waitv<3>();
      else if (tt == 61) waitv<2>();
      else if (tt == 62) waitv<1>();
      else waitv<0>();
      __builtin_amdgcn_s_barrier();
      if (tt + 7 < 64) STAGE1(tt + 7, (tt + 7) & 7);
      __builtin_amdgcn_sched_barrier(0);
      const int nt = tt >> 3, kq = tt & 7;
      if (kq == 0) {
        acc1[0] = (f32x4){0.f, 0.f, 0.f, 0.f};
        acc1[1] = (f32x4){0.f, 0.f, 0.f, 0.f};
      }
      const unsigned short* Bs = Ring + (tt & 7) * 4096;
      const int ar = rg16 + lr;
      bf16x8 af = *(const bf16x8*)
          &HLr[ar * 256 + (((kq * 4 + lg) ^ (ar & 7)) * 8)];
      bf16x8 bg[2];
#pragma unroll
      for (int n = 0; n < 2; ++n) {
        const int rb = cg32 + n * 16 + lr;  // tile-local row 0..127
        bg[n] = *(const bf16x8*)&Bs[rb * 32 + ((lg ^ ((rb >> 1) & 3)) * 8)];
      }
      __builtin_amdgcn_s_setprio(1);
#pragma unroll
      for (int n = 0; n < 2; ++n)
        acc1[n] = __builtin_amdgcn_mfma_f32_16x16x32_bf16(af, bg[n], acc1[n],
                                                          0, 0, 0);
      __builtin_amdgcn_s_setprio(0);
      if (kq == 7) {
#pragma unroll
        for (int n = 0; n < 2; ++n) {
          const int c = nt * 128 + cg32 + n * 16 + lr;
          const float cb = (nt < 4) ? Par[c] : 0.f;  // resident since tt==7
#pragma unroll
          for (int r = 0; r < 4; ++r) {
            const int row = rg16 + m04 + r;
            const float v = fsilu(acc1[n][r] + cb);
            if (nt < 4) {
              XiL[row * 512 + (((c >> 3) ^ (row & 7)) * 8) + (c & 7)] = f2b(v);
            } else {
              const int cs = c - 512;
              SzL[row * 512 + (((cs >> 3) ^ (row & 7)) * 8) + (cs & 7)] =
                  f2b(v);
            }
          }
        }
      }
      __builtin_amdgcn_sched_barrier(0);
    }
    // xwp rows 0..47 -> Ring slots 0..5 (slot 7 untouched: race-free
    // vs waves still computing tt=63; slots 0..6 last read pre-barrier(63))
#pragma unroll
    for (int j = 0; j < 6; ++j) {
      const int i = w * 6 + j;  // 48 gl16, 1 row (1KB) each
      gl16(xwp + (long)i * 512 + (lane ^ (i & 7)) * 8, Ring + i * 512);
    }
    lgkm_bar();  // Xi/Sz visible; all Ring tile-reads retired

    // ====== P2: xdbl = xi @ xwp^T; dtwp half1 rides under P2's MFMA ======
#pragma unroll
    for (int j = 0; j < 2; ++j) {  // dtwp rows 0..255 -> Ring[24576..32768)
      const int u = w * 2 + j;
      const int row = u * 16 + (lane >> 2);
      const int c = (lane & 3) ^ (row & 3);
      gl16(dtwp + (long)row * 32 + c * 8, Ring + 24576 + u * 512);
    }
    waitv<2>();  // xwp landed; dtwp-h1 in flight (its dest region is only
                 // read by fn2==3 waves whose Dxl cols 48..63 are unused)
    __builtin_amdgcn_s_barrier();
    {
      const int fm2 = w & 1, fn2 = w >> 1;
      const int ar = fm2 * 16 + lr, rb = fn2 * 16 + lr;
      f32x4 a2 = {0.f, 0.f, 0.f, 0.f};
      __builtin_amdgcn_s_setprio(1);
#pragma unroll
      for (int kc = 0; kc < 16; ++kc) {
        bf16x8 af = *(const bf16x8*)
            &XiL[ar * 512 + (((kc * 4 + lg) ^ (lr & 7)) * 8)];
        bf16x8 bg = *(const bf16x8*)
            &Ring[rb * 512 + (((kc * 4 + lg) ^ (lr & 7)) * 8)];
        a2 = __builtin_amdgcn_mfma_f32_16x16x32_bf16(af, bg, a2, 0, 0, 0);
      }
      __builtin_amdgcn_s_setprio(0);
#pragma unroll
      for (int r = 0; r < 4; ++r)
        Dxl[(fm2 * 16 + m04 + r) * 68 + fn2 * 16 + lr] = a2[r];
    }
    lgkm_bar();  // Dxl visible; Ring reads retired

    // ===== dtwp half2 (rows 256..511) -> Ring[0..8192); overlap BC/afdt ===
#pragma unroll
    for (int j = 0; j < 2; ++j) {
      const int u = w * 2 + j;
      const int row = 256 + u * 16 + (lane >> 2);
      const int c = (lane & 3) ^ (row & 3);
      gl16(dtwp + (long)row * 32 + c * 8, Ring + u * 512);
    }
    if (t < 32) {
      float bc2 = 0.f;
      const float* dx = &Dxl[t * 68];
#pragma unroll
      for (int s2 = 0; s2 < 16; ++s2) bc2 += dx[16 + s2] * dx[32 + s2];
      BCl[t] = bc2;
    }
    bf16x8 afdt;
    {
      // k 16..31 multiply vs zero-padded dtwp cols: contribute 0
      const float* dx = &Dxl[((w & 1) * 16 + lr) * 68 + lg * 8];
#pragma unroll
      for (int e = 0; e < 8; ++e) afdt[e] = (short)f2b(dx[e]);
    }
    waitv<0>();
    lgkm_bar();  // dtwp halves + BCl visible

    // ===== P4: dt = softplus(xdbl[:,:16]@dtwp^T + dtb); y (barrier-free) ==
    {
      const int fn4 = w >> 1, m04b = (w & 1) * 16 + m04;
#pragma unroll
      for (int tt = 0; tt < 8; ++tt) {
        const int d = tt * 64 + fn4 * 16 + lr;
        const unsigned short* dbase = (tt < 4) ? (Ring + 24576) : Ring;
        const int doff = (tt < 4) ? d : (d - 256);
        bf16x8 bg =
            *(const bf16x8*)&dbase[doff * 32 + ((lg ^ (d & 3)) * 8)];
        f32x4 da = __builtin_amdgcn_mfma_f32_16x16x32_bf16(
            afdt, bg, (f32x4){0.f, 0.f, 0.f, 0.f}, 0, 0, 0);
        const float dbv = Par[512 + d], dvv = Par[1024 + d];
#pragma unroll
        for (int r = 0; r < 4; ++r) {
          const int row = m04b + r;
          const float dtv = fsoftplus(da[r] + dbv);
          const int xoff = row * 512 + (((d >> 3) ^ (row & 7)) * 8) + (d & 7);
          // SzL shares XiL's swizzle -> same offset formula (== xoff)
          const float y = b2f(XiL[xoff]) * (dtv * BCl[row] + dvv) *
                          b2f(SzL[xoff]);
          XiL[xoff] = f2b(y);  // y overwrites xi in place
        }
      }
    }
    lgkm_bar();  // y visible; dtwp reads retired

    // ===== P5: h += y @ ow^T. 32 tiles [128N x 32K], depth-7 =====
    auto STAGE5 = [&](int tt, int slot) {
      const int ng = tt >> 4, kq = tt & 15;
      gl16(ow + (long)(ng * 128 + w * 16 + strow) * 512 + kq * 32 + stc * 8,
           Ring + slot * 4096 + w * 512);
    };
    STAGE5(0, 0); STAGE5(1, 1); STAGE5(2, 2); STAGE5(3, 3);
    STAGE5(4, 4); STAGE5(5, 5); STAGE5(6, 6);
    f32x4 acc5[2];
#pragma unroll
    for (int tt = 0; tt < 32; ++tt) {
      if (tt <= 25) waitv<6>();
      else if (tt == 26) waitv<5>();
      else if (tt == 27) waitv<4>();
      else if (tt == 28) waitv<3>();
      else if (tt == 29) waitv<2>();
      else if (tt == 30) waitv<1>();
      else waitv<0>();
      __builtin_amdgcn_s_barrier();
      if (tt + 7 < 32) STAGE5(tt + 7, (tt + 7) & 7);
      __builtin_amdgcn_sched_barrier(0);
      const int ng = tt >> 4, kq = tt & 15;
      if (kq == 0) {
        acc5[0] = (f32x4){0.f, 0.f, 0.f, 0.f};
        acc5[1] = (f32x4){0.f, 0.f, 0.f, 0.f};
      }
      const unsigned short* Bs = Ring + (tt & 7) * 4096;
      const int ar = rg16 + lr;
      bf16x8 af = *(const bf16x8*)
          &XiL[ar * 512 + (((kq * 4 + lg) ^ (ar & 7)) * 8)];
      bf16x8 bg[2];
#pragma unroll
      for (int n = 0; n < 2; ++n) {
        const int rb = cg32 + n * 16 + lr;
        bg[n] = *(const bf16x8*)&Bs[rb * 32 + ((lg ^ ((rb >> 1) & 3)) * 8)];
      }
      __builtin_amdgcn_s_setprio(1);
#pragma unroll
      for (int n = 0; n < 2; ++n)
        acc5[n] = __builtin_amdgcn_mfma_f32_16x16x32_bf16(af, bg[n], acc5[n],
                                                          0, 0, 0);
      __builtin_amdgcn_s_setprio(0);
      if (kq == 15) {
#pragma unroll
        for (int n = 0; n < 2; ++n) {
          const int col = ng * 128 + cg32 + n * 16 + lr;
#pragma unroll
          for (int r = 0; r < 4; ++r) {
            const int row = rg16 + m04 + r;
            const float v = acc5[n][r] + hres[ng][n][r];
            hres[ng][n][r] = v;
            HLr[row * 256 + (((col >> 3) ^ (row & 7)) * 8) + (col & 7)] =
                f2b(v);
          }
        }
      }
      __builtin_amdgcn_sched_barrier(0);
    }
    // next blk's P1 tiles 0..6 -> slots 0..6 (slot 7 untouched: still read
    // at tt=31; slots 0..6 last read at tiles 24..30, pre-barrier(31))
    if (blk < 4) {
      const unsigned short* inw_n = inwb + (long)(blk + 1) * 1024 * 256;
#pragma unroll
      for (int j = 0; j < 7; ++j)
        gl16(inw_n + (long)(w * 16 + strow) * 256 + j * 32 + stc * 8,
             Ring + j * 4096 + w * 512);
    }
    lgkm_bar();  // new h visible for next blk's P1
  }

  // ===== fused epilogue: LN(256) + classifier, h from regs via Ring =====
  {
    float* Rf = (float*)Ring;  // 32 rows x 256 f32 = 32KB (Ring is free)
#pragma unroll
    for (int ng = 0; ng < 2; ++ng)
#pragma unroll
      for (int n = 0; n < 2; ++n)
#pragma unroll
        for (int r = 0; r < 4; ++r)
          Rf[(rg16 + m04 + r) * 256 + ng * 128 + cg32 + n * 16 + lr] =
              hres[ng][n][r];
    lgkm_bar();  // Rf visible
    // each wave: 4 rows; lane reads float4 (16B) -> conflict-free
#pragma unroll
    for (int rr = 0; rr < 4; ++rr) {
      const int row = w * 4 + rr;
      float4v v = ((const float4v*)(Rf + row * 256))[lane];
      float s = v[0] + v[1] + v[2] + v[3];
#pragma unroll
      for (int o = 32; o; o >>= 1) s += __shfl_xor(s, o);
      const float mu = s * (1.f / 256.f);
      float d0 = v[0] - mu, d1 = v[1] - mu, d2 = v[2] - mu, d3 = v[3] - mu;
      float qq = d0 * d0 + d1 * d1 + d2 * d2 + d3 * d3;
#pragma unroll
      for (int o = 32; o; o >>= 1) qq += __shfl_xor(qq, o);
      const float rs = rsqrtf(qq * (1.f / 256.f) + 1e-5f);
      const float4v gv = ((const float4v*)ln_g)[lane];
      const float4v bv = ((const float4v*)ln_b)[lane];
      float hn[4];
      hn[0] = d0 * rs * gv[0] + bv[0];
      hn[1] = d1 * rs * gv[1] + bv[1];
      hn[2] = d2 * rs * gv[2] + bv[2];
      hn[3] = d3 * rs * gv[3] + bv[3];
      float lgt[8];
#pragma unroll
      for (int o = 0; o < 8; ++o) {
        const float4v wv = ((const float4v*)(Wc + o * 256))[lane];
        float p = hn[0] * wv[0] + hn[1] * wv[1] + hn[2] * wv[2] + hn[3] * wv[3];
#pragma unroll
        for (int x = 32; x; x >>= 1) p += __shfl_xor(p, x);
        lgt[o] = p;
      }
      if (lane == 0) {
#pragma unroll
        for (int o = 0; o < 8; ++o)
          out[(long)(bm + row) * 8 + o] = lgt[o] + bc[o];
      }
    }
  }
}

// ---------------------------------------------------------------------------
// prep: merged weight-precast + x cast (one launch, overlapping BW streams).
// Blocks [0, 2672): precast (W_pre -> bf16; in_w -> bf16 with conv tap3
//   folded into rows <512; out_w -> bf16; x_proj padded [64x512]; dt_w
//   padded [512x32]). Blocks [2672, 4720): x fp32 -> bf16 (grid-stride 2048).
// ---------------------------------------------------------------------------
__global__ __launch_bounds__(256) void prep(
    const float* __restrict__ wpre, const float* __restrict__ inw,
    const float* __restrict__ ow, const float* __restrict__ xw,
    const float* __restrict__ dtw, const float* __restrict__ cw,
    const float* __restrict__ x,
    unsigned short* __restrict__ wpreb, unsigned short* __restrict__ inwb,
    unsigned short* __restrict__ owb, unsigned short* __restrict__ xwpb,
    unsigned short* __restrict__ dtwpb, unsigned short* __restrict__ xb) {
  if (blockIdx.x < 2672) {
    const int S0 = 524288;         // 256*2048
    const int S1 = S0 + 1310720;   // + 5*1024*256
    const int S2 = S1 + 655360;    // + 5*256*512
    const int S3 = S2 + 163840;    // + 5*64*512
    const int S4 = S3 + 81920;     // + 5*512*32
    int i4 = (blockIdx.x * 256 + threadIdx.x) * 4;
    if (i4 >= S4) return;
    float4v v = {0.f, 0.f, 0.f, 0.f};
    unsigned short* dst;
    if (i4 < S0) {
      v = *(const float4v*)(wpre + i4);
      dst = wpreb + i4;
    } else if (i4 < S1) {
      int o = i4 - S0;
      v = *(const float4v*)(inw + o);
      int b = o >> 18, row = (o >> 8) & 1023;
      if (row < 512) {
        float c3 = cw[(b * 512 + row) * 4 + 3];
        v[0] *= c3; v[1] *= c3; v[2] *= c3; v[3] *= c3;
      }
      dst = inwb + o;
    } else if (i4 < S2) {
      int o = i4 - S1;
      v = *(const float4v*)(ow + o);
      dst = owb + o;
    } else if (i4 < S3) {
      int o = i4 - S2;
      dst = xwpb + o;
      int k = o & 511, j = (o >> 9) & 63, b = o >> 15;
      if (j < 48) v = *(const float4v*)(xw + ((long)(b * 48 + j)) * 512 + k);
    } else {
      int o = i4 - S3;
      dst = dtwpb + o;
      int k = o & 31, dd = o >> 5;
      if (k < 16) v = *(const float4v*)(dtw + (long)dd * 16 + k);
    }
    s16x4 sv;
    sv[0] = (short)f2b(v[0]); sv[1] = (short)f2b(v[1]);
    sv[2] = (short)f2b(v[2]); sv[3] = (short)f2b(v[3]);
    *(s16x4*)dst = sv;
  } else {
    const int bid = blockIdx.x - 2672;
    const int n4 = (8192 * 2048) / 4;
    for (int i = bid * 256 + threadIdx.x; i < n4; i += 2048 * 256) {
      float4v v = ((const float4v*)x)[i];
      s16x4 o;
      o[0] = (short)f2b(v[0]); o[1] = (short)f2b(v[1]);
      o[2] = (short)f2b(v[2]); o[3] = (short)f2b(v[3]);
      ((s16x4*)xb)[i] = o;
    }
  }
}

extern "C" void kernel_launch(void* const* d_in, const int* in_sizes, int n_in,
                              void* d_out, int out_size, void* d_ws,
                              size_t ws_size, hipStream_t stream) {
  const float* x      = (const float*)d_in[0];
  const float* W_pre  = (const float*)d_in[1];
  const float* b_pre  = (const float*)d_in[2];
  const float* in_w   = (const float*)d_in[3];
  const float* conv_w = (const float*)d_in[4];
  const float* conv_b = (const float*)d_in[5];
  const float* x_w    = (const float*)d_in[6];
  const float* dt_w   = (const float*)d_in[7];
  const float* dt_b   = (const float*)d_in[8];
  // d_in[9] = A_log: dead (scan starts from h0=0 and L=1)
  const float* Dp     = (const float*)d_in[10];
  const float* out_w  = (const float*)d_in[11];
  const float* ln_g   = (const float*)d_in[12];
  const float* ln_b   = (const float*)d_in[13];
  const float* W_cls  = (const float*)d_in[14];
  const float* b_cls  = (const float*)d_in[15];
  float* out = (float*)d_out;

  char* w = (char*)d_ws;
  unsigned short* wpreb = (unsigned short*)w; w += 256 * 2048 * 2;
  unsigned short* inwb  = (unsigned short*)w; w += 5 * 1024 * 256 * 2;
  unsigned short* xwpb  = (unsigned short*)w; w += 5 * 64 * 512 * 2;
  unsigned short* owb   = (unsigned short*)w; w += 5 * 256 * 512 * 2;
  unsigned short* dtwpb = (unsigned short*)w; w += 5 * 512 * 32 * 2;
  float*          h     = (float*)w;          w += 8192 * 256 * 4;
  unsigned short* hb    = (unsigned short*)w; w += 8192 * 256 * 2;
  unsigned short* xb    = (unsigned short*)w; w += 8192 * 2048 * 2;

  // merged weight precast + x cast (one launch, overlapping streams)
  prep<<<4720, 256, 0, stream>>>(W_pre, in_w, out_w, x_w, dt_w, conv_w, x,
                                 wpreb, inwb, owb, xwpb, dtwpb, xb);

  // h = x @ W_pre^T + b_pre  (fp32 of + bf16 ob)
  gemm_pl<128, 64><<<256, 256, 0, stream>>>(
      xb, wpreb, 256, 2048, 4, b_pre, h, hb);

  // all 5 Mamba blocks + LN + classifier, one persistent kernel
  mamba5<<<256, 512, 0, stream>>>(hb, h, inwb, xwpb, dtwpb, owb,
                                  conv_b, dt_b, Dp,
                                  ln_g, ln_b, W_cls, b_cls, out);
}

// Round 25
// 180.862 us; speedup vs baseline: 1.1443x; 1.1443x over previous
//
#include <hip/hip_runtime.h>
#include <hip/hip_bf16.h>

typedef __attribute__((ext_vector_type(8))) short bf16x8;
typedef __attribute__((ext_vector_type(4))) short s16x4;
typedef __attribute__((ext_vector_type(4))) float f32x4;
typedef __attribute__((ext_vector_type(4))) float float4v;

static __device__ __forceinline__ unsigned short f2b(float f) {
  unsigned int u = __builtin_bit_cast(unsigned int, f);
  u += 0x7fffu + ((u >> 16) & 1u);
  return (unsigned short)(u >> 16);
}
static __device__ __forceinline__ float b2f(unsigned short s) {
  unsigned int u = ((unsigned int)s) << 16;
  return __builtin_bit_cast(float, u);
}
// fast silu/softplus on TRANS pipe; bf16-accurate
static __device__ __forceinline__ float fsilu(float x) {
  float e = __builtin_amdgcn_exp2f(-1.44269504f * x);
  return x * __builtin_amdgcn_rcpf(1.f + e);
}
static __device__ __forceinline__ float fsoftplus(float a) {
  if (a > 20.f) return a;
  float t = __builtin_amdgcn_exp2f(1.44269504f * a);
  return 0.69314718f * __builtin_amdgcn_logf(1.f + t);
}
// async global->LDS, 16B/lane; dest wave-uniform base + lane*16,
// source per-lane (enables source-side swizzling, rule #21)
static __device__ __forceinline__ void gl16(const void* g, void* l) {
  __builtin_amdgcn_global_load_lds(
      (const __attribute__((address_space(1))) unsigned int*)g,
      (__attribute__((address_space(3))) unsigned int*)l, 16, 0, 0);
}
template <int N>
static __device__ __forceinline__ void waitv() {
  if constexpr (N == 0) asm volatile("s_waitcnt vmcnt(0)" ::: "memory");
  else if constexpr (N == 1) asm volatile("s_waitcnt vmcnt(1)" ::: "memory");
  else if constexpr (N == 2) asm volatile("s_waitcnt vmcnt(2)" ::: "memory");
  else if constexpr (N == 3) asm volatile("s_waitcnt vmcnt(3)" ::: "memory");
  else if constexpr (N == 4) asm volatile("s_waitcnt vmcnt(4)" ::: "memory");
  else if constexpr (N == 5) asm volatile("s_waitcnt vmcnt(5)" ::: "memory");
  else if constexpr (N == 6) asm volatile("s_waitcnt vmcnt(6)" ::: "memory");
  else if constexpr (N == 8) asm volatile("s_waitcnt vmcnt(8)" ::: "memory");
}
static __device__ __forceinline__ void lgkm_bar() {
  asm volatile("s_waitcnt lgkmcnt(0)" ::: "memory");
  __builtin_amdgcn_s_barrier();
}

// ---------------------------------------------------------------------------
// pre-GEMM: C = A @ W^T + bias, bf16 MFMA, fp32 accum. 128x64, BK=32,
// 4 waves, depth-4 ring, counted vmcnt, chunk-XOR swizzle, XCD swizzle.
// ---------------------------------------------------------------------------
template <int TM, int TN>
__global__ __launch_bounds__(256) void gemm_pl(
    const unsigned short* __restrict__ A, const unsigned short* __restrict__ W,
    int N, int K, int GY,
    const float* __restrict__ p0, float* __restrict__ of,
    unsigned short* __restrict__ ob) {
  constexpr int FM = TM / 32, FN = TN / 32;
  constexpr int IA = TM / 64, IW = TN / 64;
  constexpr int LPT = IA + IW;
  __shared__ __align__(16) unsigned short As[4][TM * 32];
  __shared__ __align__(16) unsigned short Ws[4][TN * 32];

  const int t = threadIdx.x, lane = t & 63, wave = t >> 6;
  const int lr = lane & 15;
  const int q = gridDim.x >> 3;
  const int s = (blockIdx.x & 7) * q + (blockIdx.x >> 3);
  const int bm = (s / GY) * TM, bn = (s % GY) * TN;
  const int wr = (wave >> 1) * (TM / 2), wc = (wave & 1) * (TN / 2);

  f32x4 acc[FM][FN];
#pragma unroll
  for (int i = 0; i < FM; ++i)
#pragma unroll
    for (int j = 0; j < FN; ++j) acc[i][j] = (f32x4){0.f, 0.f, 0.f, 0.f};

  const unsigned short* agB =
      A + (long)(bm + wave * (TM / 4) + (lane >> 2)) * K +
      ((lane & 3) ^ ((lane >> 3) & 3)) * 8;
  const unsigned short* wgB =
      W + (long)(bn + wave * (TN / 4) + (lane >> 2)) * K +
      ((lane & 3) ^ ((lane >> 3) & 3)) * 8;

  auto STAGE = [&](int k0, int b) {
#pragma unroll
    for (int j = 0; j < IA; ++j)
      gl16(agB + k0 + (long)j * 16 * K, &As[b][(wave * (TM / 4) + j * 16) * 32]);
#pragma unroll
    for (int j = 0; j < IW; ++j)
      gl16(wgB + k0 + (long)j * 16 * K, &Ws[b][(wave * (TN / 4) + j * 16) * 32]);
  };

  auto COMPUTE = [&](int b) {
    bf16x8 af[FM], bg[FN];
    const int sw = ((lane >> 4) ^ ((lane >> 1) & 3)) * 8;
#pragma unroll
    for (int m = 0; m < FM; ++m)
      af[m] = *(const bf16x8*)&As[b][(wr + m * 16 + lr) * 32 + sw];
#pragma unroll
    for (int n = 0; n < FN; ++n)
      bg[n] = *(const bf16x8*)&Ws[b][(wc + n * 16 + lr) * 32 + sw];
    __builtin_amdgcn_s_setprio(1);
#pragma unroll
    for (int m = 0; m < FM; ++m)
#pragma unroll
      for (int n = 0; n < FN; ++n)
        acc[m][n] = __builtin_amdgcn_mfma_f32_16x16x32_bf16(af[m], bg[n],
                                                            acc[m][n], 0, 0, 0);
    __builtin_amdgcn_s_setprio(0);
  };

  const int NT = K >> 5;
  STAGE(0, 0);
  STAGE(32, 1);
  for (int tt = 0; tt < NT; ++tt) {
    if (tt + 2 < NT) {
      STAGE((tt + 2) << 5, (tt + 2) & 3);
      waitv<2 * LPT>();
    } else if (tt + 1 < NT) {
      waitv<LPT>();
    } else {
      waitv<0>();
    }
    __builtin_amdgcn_s_barrier();
    COMPUTE(tt & 3);
    __builtin_amdgcn_sched_barrier(0);
  }

  const int m0 = bm + wr + (lane >> 4) * 4;
  const int n0 = bn + wc + lr;
#pragma unroll
  for (int mi = 0; mi < FM; ++mi)
#pragma unroll
    for (int ni = 0; ni < FN; ++ni) {
      const int n = n0 + ni * 16;
#pragma unroll
      for (int r = 0; r < 4; ++r) {
        const int m = m0 + mi * 16 + r;
        float v = acc[mi][ni][r] + p0[n];
        of[(long)m * N + n] = v;
        ob[(long)m * N + n] = f2b(v);
      }
    }
}

// ---------------------------------------------------------------------------
// mamba5: 5 Mamba blocks fused + FUSED LayerNorm/classifier epilogue.
// Grid 256 x 512thr, 32 rows/block, h resident. r13 main structure:
// DEPTH-7 pipeline, tiles [128N x 32K] = 8KB, Ring = 8 x 8KB, 1 gl16 per
// wave per tile, stage tt+7 after barrier(tt), counted vmcnt 6..0 tail.
// Wave layout: 2 row-groups x 4 col-groups. Tile swizzle chunk ^= (row>>1)&3
// both-sides. No global loads in loops (conv tap3 folded into inwb;
// cb/dtb/D in Par LDS). L=1: conv=tap3*xi+cb; scan -> y=xi*(dt*BC+D)*silu(z).
// Cross-phase hiding (slot-audited, race-free):
//  - xwp (rows 0..47 -> slots 0..5) issued AFTER the P1 loop but BEFORE the
//    lgkm_bar (slot 7, still read at tt=63, untouched).
//  - dtwp split: half1 (rows 0..255) -> Ring[24576..) issued before P2's
//    barrier with waitv<2> (region only read by fn2==3 waves whose Dxl
//    cols 48..63 are unused -> tolerated); half2 (rows 256..511) ->
//    Ring[0..8192) after P2's lgkm_bar. P4 reads switch base on tt<4.
// SzL shares XiL's chunk-XOR swizzle both-sides.
// SMEM (shorts): XiL[0,16384) SzL[16384,32768) Ring[32768,65536)
//   HLr[65536,73728) Dxl@73728(32x68 f32) BCl@78080 Par@78144(1536 f32)
// ---------------------------------------------------------------------------
__global__ __launch_bounds__(512) void mamba5(
    const unsigned short* __restrict__ hb0, const float* __restrict__ h0,
    const unsigned short* __restrict__ inwb,
    const unsigned short* __restrict__ xwpb,
    const unsigned short* __restrict__ dtwpb,
    const unsigned short* __restrict__ owb,
    const float* __restrict__ conv_b, const float* __restrict__ dt_b,
    const float* __restrict__ Dp,
    const float* __restrict__ ln_g, const float* __restrict__ ln_b,
    const float* __restrict__ Wc, const float* __restrict__ bc,
    float* __restrict__ out) {
  __shared__ __align__(16) unsigned short SMEM[81216];
  unsigned short* XiL = SMEM;
  unsigned short* SzL = SMEM + 16384;
  unsigned short* Ring = SMEM + 32768;
  unsigned short* HLr = SMEM + 65536;
  float* Dxl = (float*)(SMEM + 73728);
  float* BCl = (float*)(SMEM + 78080);
  float* Par = (float*)(SMEM + 78144);

  const int t = threadIdx.x, lane = t & 63, w = t >> 6;
  const int lr = lane & 15, lg = lane >> 4;
  const int bm = blockIdx.x * 32;
  const int m04 = lg * 4;             // frag row base within 16-row block
  const int rg16 = (w >> 2) * 16;     // wave's row group: 0 / 16
  const int cg32 = (w & 3) * 32;      // wave's col group within 128-col tile
  const int strow = lane >> 2;        // staging row within 16-row group
  const int stc = (lane & 3) ^ ((strow >> 1) & 3);  // pre-swizzled src chunk

  // ---- init: h bf16 -> HLr (chunk-swizzled); fp32 residual -> regs ----
#pragma unroll
  for (int j = 0; j < 2; ++j) {
    const int i = w * 2 + j;
    const int row = 2 * i + (lane >> 5);
    const int c = (lane & 31) ^ (row & 7);
    gl16(hb0 + (long)(bm + row) * 256 + c * 8, HLr + i * 512);
  }
  float hres[2][2][4];
#pragma unroll
  for (int ng = 0; ng < 2; ++ng)
#pragma unroll
    for (int n = 0; n < 2; ++n)
#pragma unroll
      for (int r = 0; r < 4; ++r)
        hres[ng][n][r] = h0[(long)(bm + rg16 + m04 + r) * 256 + ng * 128 +
                            cg32 + n * 16 + lr];
  waitv<0>();
  __builtin_amdgcn_s_barrier();

  for (int blk = 0; blk < 5; ++blk) {
    const unsigned short* inw = inwb + (long)blk * 1024 * 256;
    const unsigned short* xwp = xwpb + (long)blk * 64 * 512;
    const unsigned short* dtwp = dtwpb + (long)blk * 512 * 32;
    const unsigned short* ow = owb + (long)blk * 256 * 512;
    const float* cbv = conv_b + blk * 512;
    const float* dtbv = dt_b + blk * 512;
    const float* Dv = Dp + blk * 512;

    // ===== P1: xz = h @ in_w'^T. 64 tiles [128N x 32K], depth-7 =====
    auto STAGE1 = [&](int tt, int slot) {
      const int nt = tt >> 3, kq = tt & 7;
      gl16(inw + (long)(nt * 128 + w * 16 + strow) * 256 + kq * 32 + stc * 8,
           Ring + slot * 4096 + w * 512);
    };
    if (w < 6) {  // params -> Par (oldest in FIFO, drained at first waitv)
      const float* ps = (w < 2) ? cbv + (w & 1) * 256
                      : (w < 4) ? dtbv + (w & 1) * 256
                                : Dv + (w & 1) * 256;
      gl16(ps + lane * 4, (unsigned short*)Par + w * 512);
    }
    STAGE1(0, 0); STAGE1(1, 1); STAGE1(2, 2); STAGE1(3, 3);
    STAGE1(4, 4); STAGE1(5, 5); STAGE1(6, 6);
    f32x4 acc1[2];
#pragma unroll
    for (int tt = 0; tt < 64; ++tt) {
      if (tt <= 57) waitv<6>();
      else if (tt == 58) waitv<5>();
      else if (tt == 59) waitv<4>();
      else if (tt == 60) waitv<3>();
      else if (tt == 61) waitv<2>();
      else if (tt == 62) waitv<1>();
      else waitv<0>();
      __builtin_amdgcn_s_barrier();
      if (tt + 7 < 64) STAGE1(tt + 7, (tt + 7) & 7);
      __builtin_amdgcn_sched_barrier(0);
      const int nt = tt >> 3, kq = tt & 7;
      if (kq == 0) {
#pragma unroll
        for (int n = 0; n < 2; ++n) {
          const int c = nt * 128 + cg32 + n * 16 + lr;
          const float cb = (nt < 4) ? Par[c] : 0.f;  // LDS (no vmcnt)
          acc1[n] = (f32x4){cb, cb, cb, cb};
        }
      }
      const unsigned short* Bs = Ring + (tt & 7) * 4096;
      const int ar = rg16 + lr;
      bf16x8 af = *(const bf16x8*)
          &HLr[ar * 256 + (((kq * 4 + lg) ^ (ar & 7)) * 8)];
      bf16x8 bg[2];
#pragma unroll
      for (int n = 0; n < 2; ++n) {
        const int rb = cg32 + n * 16 + lr;  // tile-local row 0..127
        bg[n] = *(const bf16x8*)&Bs[rb * 32 + ((lg ^ ((rb >> 1) & 3)) * 8)];
      }
      __builtin_amdgcn_s_setprio(1);
#pragma unroll
      for (int n = 0; n < 2; ++n)
        acc1[n] = __builtin_amdgcn_mfma_f32_16x16x32_bf16(af, bg[n], acc1[n],
                                                          0, 0, 0);
      __builtin_amdgcn_s_setprio(0);
      if (kq == 7) {
#pragma unroll
        for (int n = 0; n < 2; ++n) {
          const int c = nt * 128 + cg32 + n * 16 + lr;
#pragma unroll
          for (int r = 0; r < 4; ++r) {
            const int row = rg16 + m04 + r;
            const float v = fsilu(acc1[n][r]);
            if (nt < 4) {
              XiL[row * 512 + (((c >> 3) ^ (row & 7)) * 8) + (c & 7)] = f2b(v);
            } else {
              const int cs = c - 512;
              SzL[row * 512 + (((cs >> 3) ^ (row & 7)) * 8) + (cs & 7)] =
                  f2b(v);
            }
          }
        }
      }
      __builtin_amdgcn_sched_barrier(0);
    }
    // xwp rows 0..47 -> Ring slots 0..5 (slot 7 untouched: race-free
    // vs waves still computing tt=63; slots 0..6 last read pre-barrier(63))
#pragma unroll
    for (int j = 0; j < 6; ++j) {
      const int i = w * 6 + j;  // 48 gl16, 1 row (1KB) each
      gl16(xwp + (long)i * 512 + (lane ^ (i & 7)) * 8, Ring + i * 512);
    }
    lgkm_bar();  // Xi/Sz visible; all Ring tile-reads retired

    // ====== P2: xdbl = xi @ xwp^T; dtwp half1 rides under P2's MFMA ======
#pragma unroll
    for (int j = 0; j < 2; ++j) {  // dtwp rows 0..255 -> Ring[24576..32768)
      const int u = w * 2 + j;
      const int row = u * 16 + (lane >> 2);
      const int c = (lane & 3) ^ (row & 3);
      gl16(dtwp + (long)row * 32 + c * 8, Ring + 24576 + u * 512);
    }
    waitv<2>();  // xwp landed; dtwp-h1 in flight (its dest region is only
                 // read by fn2==3 waves whose Dxl cols 48..63 are unused)
    __builtin_amdgcn_s_barrier();
    {
      const int fm2 = w & 1, fn2 = w >> 1;
      const int ar = fm2 * 16 + lr, rb = fn2 * 16 + lr;
      f32x4 a2 = {0.f, 0.f, 0.f, 0.f};
      __builtin_amdgcn_s_setprio(1);
#pragma unroll
      for (int kc = 0; kc < 16; ++kc) {
        bf16x8 af = *(const bf16x8*)
            &XiL[ar * 512 + (((kc * 4 + lg) ^ (lr & 7)) * 8)];
        bf16x8 bg = *(const bf16x8*)
            &Ring[rb * 512 + (((kc * 4 + lg) ^ (lr & 7)) * 8)];
        a2 = __builtin_amdgcn_mfma_f32_16x16x32_bf16(af, bg, a2, 0, 0, 0);
      }
      __builtin_amdgcn_s_setprio(0);
#pragma unroll
      for (int r = 0; r < 4; ++r)
        Dxl[(fm2 * 16 + m04 + r) * 68 + fn2 * 16 + lr] = a2[r];
    }
    lgkm_bar();  // Dxl visible; Ring reads retired

    // ===== dtwp half2 (rows 256..511) -> Ring[0..8192); overlap BC/afdt ===
#pragma unroll
    for (int j = 0; j < 2; ++j) {
      const int u = w * 2 + j;
      const int row = 256 + u * 16 + (lane >> 2);
      const int c = (lane & 3) ^ (row & 3);
      gl16(dtwp + (long)row * 32 + c * 8, Ring + u * 512);
    }
    if (t < 32) {
      float bc2 = 0.f;
      const float* dx = &Dxl[t * 68];
#pragma unroll
      for (int s2 = 0; s2 < 16; ++s2) bc2 += dx[16 + s2] * dx[32 + s2];
      BCl[t] = bc2;
    }
    bf16x8 afdt;
    {
      // k 16..31 multiply vs zero-padded dtwp cols: contribute 0
      const float* dx = &Dxl[((w & 1) * 16 + lr) * 68 + lg * 8];
#pragma unroll
      for (int e = 0; e < 8; ++e) afdt[e] = (short)f2b(dx[e]);
    }
    waitv<0>();
    lgkm_bar();  // dtwp halves + BCl visible

    // ===== P4: dt = softplus(xdbl[:,:16]@dtwp^T + dtb); y (barrier-free) ==
    {
      const int fn4 = w >> 1, m04b = (w & 1) * 16 + m04;
#pragma unroll
      for (int tt = 0; tt < 8; ++tt) {
        const int d = tt * 64 + fn4 * 16 + lr;
        const unsigned short* dbase = (tt < 4) ? (Ring + 24576) : Ring;
        const int doff = (tt < 4) ? d : (d - 256);
        bf16x8 bg =
            *(const bf16x8*)&dbase[doff * 32 + ((lg ^ (d & 3)) * 8)];
        f32x4 da = __builtin_amdgcn_mfma_f32_16x16x32_bf16(
            afdt, bg, (f32x4){0.f, 0.f, 0.f, 0.f}, 0, 0, 0);
        const float dbv = Par[512 + d], dvv = Par[1024 + d];
#pragma unroll
        for (int r = 0; r < 4; ++r) {
          const int row = m04b + r;
          const float dtv = fsoftplus(da[r] + dbv);
          const int xoff = row * 512 + (((d >> 3) ^ (row & 7)) * 8) + (d & 7);
          // SzL shares XiL's swizzle -> same offset formula (== xoff)
          const float y = b2f(XiL[xoff]) * (dtv * BCl[row] + dvv) *
                          b2f(SzL[xoff]);
          XiL[xoff] = f2b(y);  // y overwrites xi in place
        }
      }
    }
    lgkm_bar();  // y visible; dtwp reads retired

    // ===== P5: h += y @ ow^T. 32 tiles [128N x 32K], depth-7 =====
    auto STAGE5 = [&](int tt, int slot) {
      const int ng = tt >> 4, kq = tt & 15;
      gl16(ow + (long)(ng * 128 + w * 16 + strow) * 512 + kq * 32 + stc * 8,
           Ring + slot * 4096 + w * 512);
    };
    STAGE5(0, 0); STAGE5(1, 1); STAGE5(2, 2); STAGE5(3, 3);
    STAGE5(4, 4); STAGE5(5, 5); STAGE5(6, 6);
    f32x4 acc5[2];
#pragma unroll
    for (int tt = 0; tt < 32; ++tt) {
      if (tt <= 25) waitv<6>();
      else if (tt == 26) waitv<5>();
      else if (tt == 27) waitv<4>();
      else if (tt == 28) waitv<3>();
      else if (tt == 29) waitv<2>();
      else if (tt == 30) waitv<1>();
      else waitv<0>();
      __builtin_amdgcn_s_barrier();
      if (tt + 7 < 32) STAGE5(tt + 7, (tt + 7) & 7);
      __builtin_amdgcn_sched_barrier(0);
      const int ng = tt >> 4, kq = tt & 15;
      if (kq == 0) {
        acc5[0] = (f32x4){0.f, 0.f, 0.f, 0.f};
        acc5[1] = (f32x4){0.f, 0.f, 0.f, 0.f};
      }
      const unsigned short* Bs = Ring + (tt & 7) * 4096;
      const int ar = rg16 + lr;
      bf16x8 af = *(const bf16x8*)
          &XiL[ar * 512 + (((kq * 4 + lg) ^ (ar & 7)) * 8)];
      bf16x8 bg[2];
#pragma unroll
      for (int n = 0; n < 2; ++n) {
        const int rb = cg32 + n * 16 + lr;
        bg[n] = *(const bf16x8*)&Bs[rb * 32 + ((lg ^ ((rb >> 1) & 3)) * 8)];
      }
      __builtin_amdgcn_s_setprio(1);
#pragma unroll
      for (int n = 0; n < 2; ++n)
        acc5[n] = __builtin_amdgcn_mfma_f32_16x16x32_bf16(af, bg[n], acc5[n],
                                                          0, 0, 0);
      __builtin_amdgcn_s_setprio(0);
      if (kq == 15) {
#pragma unroll
        for (int n = 0; n < 2; ++n) {
          const int col = ng * 128 + cg32 + n * 16 + lr;
#pragma unroll
          for (int r = 0; r < 4; ++r) {
            const int row = rg16 + m04 + r;
            const float v = acc5[n][r] + hres[ng][n][r];
            hres[ng][n][r] = v;
            HLr[row * 256 + (((col >> 3) ^ (row & 7)) * 8) + (col & 7)] =
                f2b(v);
          }
        }
      }
      __builtin_amdgcn_sched_barrier(0);
    }
    lgkm_bar();  // new h visible for next blk's P1
  }

  // ===== fused epilogue: LN(256) + classifier, h from regs via Ring =====
  {
    float* Rf = (float*)Ring;  // 32 rows x 256 f32 = 32KB (Ring is free)
#pragma unroll
    for (int ng = 0; ng < 2; ++ng)
#pragma unroll
      for (int n = 0; n < 2; ++n)
#pragma unroll
        for (int r = 0; r < 4; ++r)
          Rf[(rg16 + m04 + r) * 256 + ng * 128 + cg32 + n * 16 + lr] =
              hres[ng][n][r];
    lgkm_bar();  // Rf visible
    // each wave: 4 rows; lane reads float4 (16B) -> conflict-free
#pragma unroll
    for (int rr = 0; rr < 4; ++rr) {
      const int row = w * 4 + rr;
      float4v v = ((const float4v*)(Rf + row * 256))[lane];
      float s = v[0] + v[1] + v[2] + v[3];
#pragma unroll
      for (int o = 32; o; o >>= 1) s += __shfl_xor(s, o);
      const float mu = s * (1.f / 256.f);
      float d0 = v[0] - mu, d1 = v[1] - mu, d2 = v[2] - mu, d3 = v[3] - mu;
      float qq = d0 * d0 + d1 * d1 + d2 * d2 + d3 * d3;
#pragma unroll
      for (int o = 32; o; o >>= 1) qq += __shfl_xor(qq, o);
      const float rs = rsqrtf(qq * (1.f / 256.f) + 1e-5f);
      const float4v gv = ((const float4v*)ln_g)[lane];
      const float4v bv = ((const float4v*)ln_b)[lane];
      float hn[4];
      hn[0] = d0 * rs * gv[0] + bv[0];
      hn[1] = d1 * rs * gv[1] + bv[1];
      hn[2] = d2 * rs * gv[2] + bv[2];
      hn[3] = d3 * rs * gv[3] + bv[3];
      float lgt[8];
#pragma unroll
      for (int o = 0; o < 8; ++o) {
        const float4v wv = ((const float4v*)(Wc + o * 256))[lane];
        float p = hn[0] * wv[0] + hn[1] * wv[1] + hn[2] * wv[2] + hn[3] * wv[3];
#pragma unroll
        for (int x = 32; x; x >>= 1) p += __shfl_xor(p, x);
        lgt[o] = p;
      }
      if (lane == 0) {
#pragma unroll
        for (int o = 0; o < 8; ++o)
          out[(long)(bm + row) * 8 + o] = lgt[o] + bc[o];
      }
    }
  }
}

// ---------------------------------------------------------------------------
// prep: merged weight-precast + x cast (one launch, overlapping BW streams).
// Blocks [0, 2672): precast (W_pre -> bf16; in_w -> bf16 with conv tap3
//   folded into rows <512; out_w -> bf16; x_proj padded [64x512]; dt_w
//   padded [512x32]). Blocks [2672, 4720): x fp32 -> bf16 (grid-stride 2048).
// ---------------------------------------------------------------------------
__global__ __launch_bounds__(256) void prep(
    const float* __restrict__ wpre, const float* __restrict__ inw,
    const float* __restrict__ ow, const float* __restrict__ xw,
    const float* __restrict__ dtw, const float* __restrict__ cw,
    const float* __restrict__ x,
    unsigned short* __restrict__ wpreb, unsigned short* __restrict__ inwb,
    unsigned short* __restrict__ owb, unsigned short* __restrict__ xwpb,
    unsigned short* __restrict__ dtwpb, unsigned short* __restrict__ xb) {
  if (blockIdx.x < 2672) {
    const int S0 = 524288;         // 256*2048
    const int S1 = S0 + 1310720;   // + 5*1024*256
    const int S2 = S1 + 655360;    // + 5*256*512
    const int S3 = S2 + 163840;    // + 5*64*512
    const int S4 = S3 + 81920;     // + 5*512*32
    int i4 = (blockIdx.x * 256 + threadIdx.x) * 4;
    if (i4 >= S4) return;
    float4v v = {0.f, 0.f, 0.f, 0.f};
    unsigned short* dst;
    if (i4 < S0) {
      v = *(const float4v*)(wpre + i4);
      dst = wpreb + i4;
    } else if (i4 < S1) {
      int o = i4 - S0;
      v = *(const float4v*)(inw + o);
      int b = o >> 18, row = (o >> 8) & 1023;
      if (row < 512) {
        float c3 = cw[(b * 512 + row) * 4 + 3];
        v[0] *= c3; v[1] *= c3; v[2] *= c3; v[3] *= c3;
      }
      dst = inwb + o;
    } else if (i4 < S2) {
      int o = i4 - S1;
      v = *(const float4v*)(ow + o);
      dst = owb + o;
    } else if (i4 < S3) {
      int o = i4 - S2;
      dst = xwpb + o;
      int k = o & 511, j = (o >> 9) & 63, b = o >> 15;
      if (j < 48) v = *(const float4v*)(xw + ((long)(b * 48 + j)) * 512 + k);
    } else {
      int o = i4 - S3;
      dst = dtwpb + o;
      int k = o & 31, dd = o >> 5;
      if (k < 16) v = *(const float4v*)(dtw + (long)dd * 16 + k);
    }
    s16x4 sv;
    sv[0] = (short)f2b(v[0]); sv[1] = (short)f2b(v[1]);
    sv[2] = (short)f2b(v[2]); sv[3] = (short)f2b(v[3]);
    *(s16x4*)dst = sv;
  } else {
    const int bid = blockIdx.x - 2672;
    const int n4 = (8192 * 2048) / 4;
    for (int i = bid * 256 + threadIdx.x; i < n4; i += 2048 * 256) {
      float4v v = ((const float4v*)x)[i];
      s16x4 o;
      o[0] = (short)f2b(v[0]); o[1] = (short)f2b(v[1]);
      o[2] = (short)f2b(v[2]); o[3] = (short)f2b(v[3]);
      ((s16x4*)xb)[i] = o;
    }
  }
}

extern "C" void kernel_launch(void* const* d_in, const int* in_sizes, int n_in,
                              void* d_out, int out_size, void* d_ws,
                              size_t ws_size, hipStream_t stream) {
  const float* x      = (const float*)d_in[0];
  const float* W_pre  = (const float*)d_in[1];
  const float* b_pre  = (const float*)d_in[2];
  const float* in_w   = (const float*)d_in[3];
  const float* conv_w = (const float*)d_in[4];
  const float* conv_b = (const float*)d_in[5];
  const float* x_w    = (const float*)d_in[6];
  const float* dt_w   = (const float*)d_in[7];
  const float* dt_b   = (const float*)d_in[8];
  // d_in[9] = A_log: dead (scan starts from h0=0 and L=1)
  const float* Dp     = (const float*)d_in[10];
  const float* out_w  = (const float*)d_in[11];
  const float* ln_g   = (const float*)d_in[12];
  const float* ln_b   = (const float*)d_in[13];
  const float* W_cls  = (const float*)d_in[14];
  const float* b_cls  = (const float*)d_in[15];
  float* out = (float*)d_out;

  char* w = (char*)d_ws;
  unsigned short* wpreb = (unsigned short*)w; w += 256 * 2048 * 2;
  unsigned short* inwb  = (unsigned short*)w; w += 5 * 1024 * 256 * 2;
  unsigned short* xwpb  = (unsigned short*)w; w += 5 * 64 * 512 * 2;
  unsigned short* owb   = (unsigned short*)w; w += 5 * 256 * 512 * 2;
  unsigned short* dtwpb = (unsigned short*)w; w += 5 * 512 * 32 * 2;
  float*          h     = (float*)w;          w += 8192 * 256 * 4;
  unsigned short* hb    = (unsigned short*)w; w += 8192 * 256 * 2;
  unsigned short* xb    = (unsigned short*)w; w += 8192 * 2048 * 2;

  // merged weight precast + x cast (one launch, overlapping streams)
  prep<<<4720, 256, 0, stream>>>(W_pre, in_w, out_w, x_w, dt_w, conv_w, x,
                                 wpreb, inwb, owb, xwpb, dtwpb, xb);

  // h = x @ W_pre^T + b_pre  (fp32 of + bf16 ob)
  gemm_pl<128, 64><<<256, 256, 0, stream>>>(
      xb, wpreb, 256, 2048, 4, b_pre, h, hb);

  // all 5 Mamba blocks + LN + classifier, one persistent kernel
  mamba5<<<256, 512, 0, stream>>>(hb, h, inwb, xwpb, dtwpb, owb,
                                  conv_b, dt_b, Dp,
                                  ln_g, ln_b, W_cls, b_cls, out);
}